// Round 6
// baseline (678.267 us; speedup 1.0000x reference)
//
#include <hip/hip_runtime.h>
#include <math.h>

#define HID 1024
#define FF  2048
#define NE  8
#define NT  8192
#define MAXTILE 160

typedef __attribute__((ext_vector_type(4))) float f32x4;
typedef __bf16 bf16x8 __attribute__((ext_vector_type(8)));

// async global->LDS DMA, 16B per lane, dest = wave-uniform base + lane*16
#define GLL(g, l) __builtin_amdgcn_global_load_lds( \
    (const __attribute__((address_space(1))) unsigned int*)(g), \
    (__attribute__((address_space(3))) unsigned int*)(l), 16, 0, 0)

static __device__ __forceinline__ ushort f2b(float f){
  union { float f; unsigned int u; } v; v.f = f;
  unsigned int r = (v.u + 0x7FFFu + ((v.u >> 16) & 1u)) >> 16;
  return (ushort)r;
}

// -------- 64x64 tile transpose + fp32->bf16: src[e][K][N] -> dst[e][N][K] --------
__global__ __launch_bounds__(256) void k_transpose(
    const float* __restrict__ src, ushort* __restrict__ dst, int K, int N){
  __shared__ __align__(16) ushort Tt[64][72];
  int e = blockIdx.z;
  int n0 = blockIdx.x * 64, k0 = blockIdx.y * 64;
  int t = threadIdx.x;
  int r = t >> 2, c = (t & 3) * 16;
  const float* s = src + (size_t)e*K*N + (size_t)(k0+r)*N + n0 + c;
  #pragma unroll
  for (int q = 0; q < 4; ++q){
    float4 v = *(const float4*)(s + q*4);
    Tt[r][c+q*4+0] = f2b(v.x); Tt[r][c+q*4+1] = f2b(v.y);
    Tt[r][c+q*4+2] = f2b(v.z); Tt[r][c+q*4+3] = f2b(v.w);
  }
  __syncthreads();
  ushort tmp[16];
  #pragma unroll
  for (int i = 0; i < 16; ++i) tmp[i] = Tt[c+i][r];
  ushort* d = dst + (size_t)e*N*K + (size_t)(n0+r)*K + k0 + c;
  *(uint4*)(d)     = *(uint4*)&tmp[0];
  *(uint4*)(d + 8) = *(uint4*)&tmp[8];
}

// -------- Router (fp64 accum for exact top-k) + fused x->bf16 convert --------
__global__ __launch_bounds__(256) void k_router(
    const float* __restrict__ x, const float* __restrict__ Wr,
    const float* __restrict__ br, int* __restrict__ topi,
    float* __restrict__ topw, ushort* __restrict__ xb){
  __shared__ __align__(16) float sW[HID*NE];   // 32 KB
  int tid = threadIdx.x;
  const uint4* srcW = (const uint4*)Wr;
  uint4* dstW = (uint4*)sW;
  #pragma unroll
  for (int i = 0; i < 8; ++i) dstW[tid*8+i] = srcW[tid*8+i];

  // fused convert: this block's 4 token rows (4096 floats), 16 per thread
  {
    size_t base = (size_t)blockIdx.x * 4 * HID + (size_t)tid * 16;
    const float* xs = x + base;
    ushort o[16];
    #pragma unroll
    for (int j = 0; j < 16; ++j) o[j] = f2b(xs[j]);
    *(uint4*)(xb + base)     = *(uint4*)&o[0];
    *(uint4*)(xb + base + 8) = *(uint4*)&o[8];
  }
  __syncthreads();
  int wave = tid >> 6, lane = tid & 63;
  int t = blockIdx.x * 4 + wave;
  const float* xrow = x + (size_t)t * HID;
  double acc[NE];
  #pragma unroll
  for (int e=0;e<NE;++e) acc[e]=0.0;
  for (int it = 0; it < HID/64; ++it){
    int h = it*64 + lane;
    double xv = (double)xrow[h];
    #pragma unroll
    for (int e=0;e<NE;++e) acc[e] += xv * (double)sW[h*NE+e];
  }
  #pragma unroll
  for (int off=32; off>0; off>>=1){
    #pragma unroll
    for (int e=0;e<NE;++e) acc[e] += __shfl_down(acc[e], off, 64);
  }
  if (lane == 0){
    double lg[NE], p[NE];
    double m = -1e300;
    #pragma unroll
    for (int e=0;e<NE;++e){ lg[e] = acc[e] + (double)br[e]; m = fmax(m, lg[e]); }
    double s = 0.0;
    #pragma unroll
    for (int e=0;e<NE;++e){ p[e] = exp(lg[e]-m); s += p[e]; }
    double inv = 1.0 / s;
    #pragma unroll
    for (int e=0;e<NE;++e) p[e] *= inv;
    int i0 = 0;
    #pragma unroll
    for (int e=1;e<NE;++e) if (p[e] > p[i0]) i0 = e;     // strict >: lowest index on tie
    int i1 = -1;
    #pragma unroll
    for (int e=0;e<NE;++e){ if (e==i0) continue; if (i1 < 0 || p[e] > p[i1]) i1 = e; }
    double d = exp(p[i1] - p[i0]);     // softmax over the two top PROBABILITIES
    topi[t*2+0] = i0; topi[t*2+1] = i1;
    topw[t*2+0] = (float)(1.0 / (1.0 + d));
    topw[t*2+1] = (float)(d / (1.0 + d));
  }
}

// -------- single-block plan: counts + offsets + tile list + gather fill (ballot-based) --------
__global__ __launch_bounds__(256) void k_plan(
    const int* __restrict__ topi, const float* __restrict__ topw,
    int* __restrict__ counts, int* __restrict__ offsets,
    int* __restrict__ tile_e, int* __restrict__ tile_m, int* __restrict__ ntiles,
    int* __restrict__ tok_of, float* __restrict__ w_of){
  __shared__ int cnt[NE];
  __shared__ int cur[NE];
  int tid = threadIdx.x, lane = tid & 63;
  unsigned long long lt = (1ull << lane) - 1ull;
  int myCnt = 0;                         // lane e (<8) accumulates expert-e count
  for (int idx = tid; idx < 2*NT; idx += 256){
    int e = topi[idx];
    #pragma unroll
    for (int ee = 0; ee < NE; ++ee){
      unsigned long long m = __ballot(e == ee);
      if (lane == ee) myCnt += __popcll(m);
    }
  }
  if (tid < NE) cnt[tid] = 0;
  __syncthreads();
  if (lane < NE) atomicAdd(&cnt[lane], myCnt);
  __syncthreads();
  if (tid == 0){
    int run = 0, nt = 0;
    for (int e = 0; e < NE; ++e){
      int c = cnt[e];
      counts[e] = c; offsets[e] = run; cur[e] = run;
      for (int m0 = 0; m0 < c; m0 += 128){ tile_e[nt] = e; tile_m[nt] = m0; ++nt; }
      run += c;
    }
    *ntiles = nt;
  }
  __syncthreads();
  for (int idx = tid; idx < 2*NT; idx += 256){
    int e = topi[idx];
    int pos = 0;
    #pragma unroll
    for (int ee = 0; ee < NE; ++ee){
      unsigned long long m = __ballot(e == ee);
      int c = __popcll(m);
      int b = 0;
      if (lane == ee && c) b = atomicAdd(&cur[ee], c);
      b = __shfl(b, ee, 64);
      if (e == ee) pos = b + (int)__popcll(m & lt);
    }
    tok_of[pos] = idx >> 1;
    w_of[pos] = topw[idx];
  }
}

// -------- GEMM1: h = gelu(gather(x) @ W1[e] + b1[e]); BK=64, 32 MFMA per barrier --------
__global__ __launch_bounds__(256) void k_gemm1(
    const ushort* __restrict__ x, const ushort* __restrict__ w1t, const float* __restrict__ b1,
    const int* __restrict__ tok_of, const int* __restrict__ offsets, const int* __restrict__ counts,
    const int* __restrict__ tile_e, const int* __restrict__ tile_m, const int* __restrict__ ntiles,
    ushort* __restrict__ hbuf){
  int ty = blockIdx.y;
  if (ty >= *ntiles) return;
  int e = tile_e[ty];
  int m0 = tile_m[ty];
  int cnt = counts[e];
  int base = offsets[e];
  int n0 = blockIdx.x * 128;
  __shared__ __align__(16) ushort As[2][128][32];   // two k-halves of a BK=64 step
  __shared__ __align__(16) ushort Bs[2][128][32];
  int tid = threadIdx.x;
  int wave = tid >> 6, lane = tid & 63;
  int srow0 = wave*32 + (lane >> 2);
  int srow1 = srow0 + 16;
  int chunk = (lane & 3) * 8;                    // ushort offset (16B chunks)
  int t0 = tok_of[base + min(m0 + srow0, cnt-1)];
  int t1 = tok_of[base + min(m0 + srow1, cnt-1)];
  const ushort* agp0 = x + (size_t)t0*HID + chunk;
  const ushort* agp1 = x + (size_t)t1*HID + chunk;
  const ushort* wb = w1t + (size_t)e*FF*HID;
  const ushort* bgp0 = wb + (size_t)(n0 + srow0)*HID + chunk;
  const ushort* bgp1 = wb + (size_t)(n0 + srow1)*HID + chunk;
  f32x4 acc[4][4];
  #pragma unroll
  for (int i=0;i<4;++i)
    #pragma unroll
    for (int j=0;j<4;++j){ acc[i][j][0]=0.f; acc[i][j][1]=0.f; acc[i][j][2]=0.f; acc[i][j][3]=0.f; }
  int wr = (wave >> 1) * 64, wc = (wave & 1) * 64;
  int lrow = lane & 15, quad = lane >> 4;
  for (int kk = 0; kk < HID; kk += 64){
    GLL(agp0 + kk,      &As[0][wave*32][0]);
    GLL(agp1 + kk,      &As[0][wave*32+16][0]);
    GLL(agp0 + kk + 32, &As[1][wave*32][0]);
    GLL(agp1 + kk + 32, &As[1][wave*32+16][0]);
    GLL(bgp0 + kk,      &Bs[0][wave*32][0]);
    GLL(bgp1 + kk,      &Bs[0][wave*32+16][0]);
    GLL(bgp0 + kk + 32, &Bs[1][wave*32][0]);
    GLL(bgp1 + kk + 32, &Bs[1][wave*32+16][0]);
    __syncthreads();
    #pragma unroll
    for (int ko = 0; ko < 2; ++ko){
      bf16x8 af[4], bfr[4];
      #pragma unroll
      for (int i=0;i<4;++i) af[i]  = *(const bf16x8*)&As[ko][wr + i*16 + lrow][quad*8];
      #pragma unroll
      for (int j=0;j<4;++j) bfr[j] = *(const bf16x8*)&Bs[ko][wc + j*16 + lrow][quad*8];
      #pragma unroll
      for (int i=0;i<4;++i)
        #pragma unroll
        for (int j=0;j<4;++j)
          acc[i][j] = __builtin_amdgcn_mfma_f32_16x16x32_bf16(af[i], bfr[j], acc[i][j], 0, 0, 0);
    }
    __syncthreads();
  }
  #pragma unroll
  for (int i=0;i<4;++i){
    #pragma unroll
    for (int rr=0; rr<4; ++rr){
      int mrel = wr + i*16 + quad*4 + rr;   // C/D: row=(lane>>4)*4+reg, col=lane&15
      if (m0 + mrel < cnt){
        size_t grow = (size_t)(base + m0 + mrel) * FF;
        #pragma unroll
        for (int j=0;j<4;++j){
          int n = n0 + wc + j*16 + lrow;
          float v = acc[i][j][rr] + b1[e*FF + n];
          float g = 0.5f * v * (1.0f + erff(v * 0.70710678118654752f));
          hbuf[grow + n] = f2b(g);
        }
      }
    }
  }
}

// -------- GEMM2: out[tok] += w * (h @ W2[e] + b2[e]); BK=32, split-K=2 --------
__global__ __launch_bounds__(256) void k_gemm2(
    const ushort* __restrict__ hbuf, const ushort* __restrict__ w2t, const float* __restrict__ b2,
    const int* __restrict__ tok_of, const float* __restrict__ w_of,
    const int* __restrict__ offsets, const int* __restrict__ counts,
    const int* __restrict__ tile_e, const int* __restrict__ tile_m, const int* __restrict__ ntiles,
    float* __restrict__ outp){
  int ty = blockIdx.y;
  if (ty >= *ntiles) return;
  int e = tile_e[ty];
  int m0 = tile_m[ty];
  int cnt = counts[e];
  int base = offsets[e];
  int n0 = blockIdx.x * 128;
  int kz = blockIdx.z;                 // split-K half
  const int KH = FF/2;                 // 1024
  __shared__ __align__(16) ushort As[128][32];
  __shared__ __align__(16) ushort Bs[128][32];
  int tid = threadIdx.x;
  int wave = tid >> 6, lane = tid & 63;
  int srow0 = wave*32 + (lane >> 2);
  int srow1 = srow0 + 16;
  int chunk = (lane & 3) * 8;
  int ar0 = base + min(m0 + srow0, cnt-1);
  int ar1 = base + min(m0 + srow1, cnt-1);
  const ushort* agp0 = hbuf + (size_t)ar0*FF + kz*KH + chunk;
  const ushort* agp1 = hbuf + (size_t)ar1*FF + kz*KH + chunk;
  const ushort* wb = w2t + (size_t)e*HID*FF;
  const ushort* bgp0 = wb + (size_t)(n0 + srow0)*FF + kz*KH + chunk;
  const ushort* bgp1 = wb + (size_t)(n0 + srow1)*FF + kz*KH + chunk;
  f32x4 acc[4][4];
  #pragma unroll
  for (int i=0;i<4;++i)
    #pragma unroll
    for (int j=0;j<4;++j){ acc[i][j][0]=0.f; acc[i][j][1]=0.f; acc[i][j][2]=0.f; acc[i][j][3]=0.f; }
  int wr = (wave >> 1) * 64, wc = (wave & 1) * 64;
  int lrow = lane & 15, quad = lane >> 4;
  for (int kk = 0; kk < KH; kk += 32){
    GLL(agp0 + kk, &As[wave*32][0]);
    GLL(agp1 + kk, &As[wave*32+16][0]);
    GLL(bgp0 + kk, &Bs[wave*32][0]);
    GLL(bgp1 + kk, &Bs[wave*32+16][0]);
    __syncthreads();
    bf16x8 af[4], bfr[4];
    #pragma unroll
    for (int i=0;i<4;++i) af[i]  = *(const bf16x8*)&As[wr + i*16 + lrow][quad*8];
    #pragma unroll
    for (int j=0;j<4;++j) bfr[j] = *(const bf16x8*)&Bs[wc + j*16 + lrow][quad*8];
    #pragma unroll
    for (int i=0;i<4;++i)
      #pragma unroll
      for (int j=0;j<4;++j)
        acc[i][j] = __builtin_amdgcn_mfma_f32_16x16x32_bf16(af[i], bfr[j], acc[i][j], 0, 0, 0);
    __syncthreads();
  }
  #pragma unroll
  for (int i=0;i<4;++i){
    #pragma unroll
    for (int rr=0; rr<4; ++rr){
      int mrel = wr + i*16 + quad*4 + rr;
      if (m0 + mrel < cnt){
        int pos = base + m0 + mrel;
        int tok = tok_of[pos];
        float wgt = w_of[pos];
        float* orow = outp + (size_t)tok * HID;
        #pragma unroll
        for (int j=0;j<4;++j){
          int n = n0 + wc + j*16 + lrow;
          float y = acc[i][j][rr] + (kz == 0 ? b2[e*HID + n] : 0.f);  // bias once
          atomicAdd(&orow[n], wgt * y);
        }
      }
    }
  }
}

extern "C" void kernel_launch(void* const* d_in, const int* in_sizes, int n_in,
                              void* d_out, int out_size, void* d_ws, size_t ws_size,
                              hipStream_t stream) {
  const float* x  = (const float*)d_in[0];   // [4,2048,1024]
  const float* Wr = (const float*)d_in[1];   // [1024,8]
  const float* br = (const float*)d_in[2];   // [8]
  const float* W1 = (const float*)d_in[3];   // [8,1024,2048]
  const float* b1 = (const float*)d_in[4];   // [8,2048]
  const float* W2 = (const float*)d_in[5];   // [8,2048,1024]
  const float* b2 = (const float*)d_in[6];   // [8,1024]
  float* out = (float*)d_out;                // [4,2048,1024] fp32

  char* w = (char*)d_ws;
  int*   counts  = (int*)(w + 0);
  int*   offsets = (int*)(w + 64);
  int*   ntiles  = (int*)(w + 128);
  int*   tile_e  = (int*)(w + 1024);
  int*   tile_m  = (int*)(w + 1024 + MAXTILE*4);
  int*   topi    = (int*)(w + 131072);
  float* topw    = (float*)(w + 196608);
  int*   tok_of  = (int*)(w + 262144);
  float* w_of    = (float*)(w + 327680);
  const size_t XB_OFF  = 524288ull;
  const size_t W1T_OFF = XB_OFF  + 16ull*1024*1024;
  const size_t W2T_OFF = W1T_OFF + 32ull*1024*1024;
  const size_t HB_OFF  = W2T_OFF + 32ull*1024*1024;   // end = 150.5 MiB
  ushort* xb   = (ushort*)(w + XB_OFF);
  ushort* W1t  = (ushort*)(w + W1T_OFF);
  ushort* W2t  = (ushort*)(w + W2T_OFF);
  ushort* hbuf = (ushort*)(w + HB_OFF);

  hipMemsetAsync(out, 0, (size_t)NT*HID*sizeof(float), stream); // gemm2 accumulates into out

  k_router<<<NT/4, 256, 0, stream>>>(x, Wr, br, topi, topw, xb);
  k_transpose<<<dim3(FF/64, HID/64, NE), 256, 0, stream>>>(W1, W1t, HID, FF);
  k_transpose<<<dim3(HID/64, FF/64, NE), 256, 0, stream>>>(W2, W2t, FF, HID);
  k_plan<<<1, 256, 0, stream>>>(topi, topw, counts, offsets, tile_e, tile_m, ntiles, tok_of, w_of);

  k_gemm1<<<dim3(FF/128, MAXTILE), 256, 0, stream>>>(xb, W1t, b1, tok_of, offsets, counts,
                                                     tile_e, tile_m, ntiles, hbuf);
  k_gemm2<<<dim3(HID/128, MAXTILE, 2), 256, 0, stream>>>(hbuf, W2t, b2, tok_of, w_of, offsets, counts,
                                                         tile_e, tile_m, ntiles, out);
}